// Round 3
// baseline (698.722 us; speedup 1.0000x reference)
//
#include <hip/hip_runtime.h>
#include <math.h>

#define LSEQ   350
#define DDIM   768
#define NPAIR  224
#define MROWS1 78400
#define NSLAB1 613   // ceil(78400/128)

typedef short bf16x8 __attribute__((ext_vector_type(8)));
typedef float f32x4  __attribute__((ext_vector_type(4)));

__device__ __forceinline__ unsigned short f2bf(float x) {
  unsigned int u = __float_as_uint(x);
  unsigned int r = (u + 0x7FFFu + ((u >> 16) & 1u)) >> 16;  // RNE
  return (unsigned short)r;
}

__device__ __forceinline__ float tanh_fast(float x) {
  float e = __expf(2.f * x);
  return 1.f - 2.f / (e + 1.f);
}

// ---------------- kernel 0: W -> Wt (transposed, bf16) ----------------
__global__ __launch_bounds__(256) void k_w1t(const float* __restrict__ W,
                                             unsigned short* __restrict__ Wt) {
  __shared__ float tile[32][33];
  int bk = blockIdx.x * 32, bn = blockIdx.y * 32;
  int tx = threadIdx.x & 31, ty = threadIdx.x >> 5;
#pragma unroll
  for (int i = 0; i < 32; i += 8)
    tile[ty + i][tx] = W[(size_t)(bk + ty + i) * DDIM + bn + tx];
  __syncthreads();
#pragma unroll
  for (int i = 0; i < 32; i += 8)
    Wt[(size_t)(bn + ty + i) * DDIM + bk + tx] = f2bf(tile[tx][ty + i]);
}

// ---------------- kernel 1: fused scores GEMM (runtime M) ----------------
// outs[row] += sum_n vv[n] * tanh( (X @ W)[row][n] + bias[n] ) over this block's n-slab
// swz=1: 1D grid 77*48. XCD-aware decode: x=b%8 (XCD under round-robin), the 6
// n-chunks of one row-slab run consecutively on the SAME XCD -> A-slab hits its L2.
__global__ __launch_bounds__(256, 2) void k_gemm_score(
    const float* __restrict__ X, const unsigned short* __restrict__ Wt,
    const float* __restrict__ bias, const float* __restrict__ vv,
    float* __restrict__ outs, int Mrows, int swz) {
  int slab, nchunk;
  if (swz) {
    int b = blockIdx.x;
    int g = b / 48, r = b - g * 48;
    slab = g * 8 + (r & 7);
    nchunk = r >> 3;
    if (slab >= NSLAB1) return;  // before any __syncthreads -> safe
  } else {
    slab = blockIdx.y;
    nchunk = blockIdx.x;
  }
  const int row0 = slab * 128;
  const int n0 = nchunk * 128;

  __shared__ unsigned short As[128][40];  // stride 40 halves = 80B -> 2-way bank alias only (free)
  __shared__ unsigned short Bs[128][40];

  const int t = threadIdx.x;
  const int l15 = t & 15;
  const int quad = (t >> 4) & 3;
  const int w = t >> 6;
  const int wm = w >> 1, wn = w & 1;

  const int ar = t >> 3;       // A staging: row within pass
  const int ac = (t & 7) * 4;  // A staging: k offset (4 floats)
  const int br = t >> 2;       // B staging: row within pass
  const int bc = (t & 3) * 8;  // B staging: k offset (8 bf16)

  f32x4 acc[4][4];
#pragma unroll
  for (int mi = 0; mi < 4; ++mi)
#pragma unroll
    for (int ni = 0; ni < 4; ++ni)
#pragma unroll
      for (int r = 0; r < 4; ++r) acc[mi][ni][r] = 0.f;

  for (int k0 = 0; k0 < DDIM; k0 += 32) {
    // stage A: 128 rows x 32 k, fp32 -> bf16 (round-half-up + v_perm pack)
#pragma unroll
    for (int pass = 0; pass < 4; ++pass) {
      int r = ar + pass * 32;
      int row = row0 + r;
      float4 x = make_float4(0.f, 0.f, 0.f, 0.f);
      if (row < Mrows) x = *(const float4*)(X + (size_t)row * DDIM + k0 + ac);
      unsigned int ux = __float_as_uint(x.x) + 0x8000u;
      unsigned int uy = __float_as_uint(x.y) + 0x8000u;
      unsigned int uz = __float_as_uint(x.z) + 0x8000u;
      unsigned int uw = __float_as_uint(x.w) + 0x8000u;
      unsigned int lo = __builtin_amdgcn_perm(uy, ux, 0x07060302u);  // {y.hi16, x.hi16}
      unsigned int hi = __builtin_amdgcn_perm(uw, uz, 0x07060302u);
      *(uint2*)&As[r][ac] = make_uint2(lo, hi);
    }
    // stage B: 128 n-rows x 32 k (bf16, [n][k])
#pragma unroll
    for (int pp = 0; pp < 2; ++pp) {
      int r = br + pp * 64;
      uint4 v = *(const uint4*)(Wt + (size_t)(n0 + r) * DDIM + k0 + bc);
      *(uint4*)&Bs[r][bc] = v;
    }
    __syncthreads();

    bf16x8 a[4], b[4];
#pragma unroll
    for (int mi = 0; mi < 4; ++mi)
      a[mi] = *(const bf16x8*)&As[wm * 64 + mi * 16 + l15][quad * 8];
#pragma unroll
    for (int ni = 0; ni < 4; ++ni)
      b[ni] = *(const bf16x8*)&Bs[wn * 64 + ni * 16 + l15][quad * 8];
#pragma unroll
    for (int mi = 0; mi < 4; ++mi)
#pragma unroll
      for (int ni = 0; ni < 4; ++ni)
        acc[mi][ni] = __builtin_amdgcn_mfma_f32_16x16x32_bf16(a[mi], b[ni], acc[mi][ni], 0, 0, 0);
    __syncthreads();
  }

  // epilogue: tanh + dot vv over this block's 128 n-cols, shuffle-reduce, atomic
  float vvv[4], bbv[4];
#pragma unroll
  for (int ni = 0; ni < 4; ++ni) {
    int n = n0 + wn * 64 + ni * 16 + l15;
    vvv[ni] = vv[n];
    bbv[ni] = bias[n];
  }
#pragma unroll
  for (int mi = 0; mi < 4; ++mi) {
#pragma unroll
    for (int reg = 0; reg < 4; ++reg) {
      float s = 0.f;
#pragma unroll
      for (int ni = 0; ni < 4; ++ni)
        s += tanh_fast(acc[mi][ni][reg] + bbv[ni]) * vvv[ni];
      s += __shfl_xor(s, 1);
      s += __shfl_xor(s, 2);
      s += __shfl_xor(s, 4);
      s += __shfl_xor(s, 8);
      if (l15 == mi * 4 + reg) {
        int row = row0 + wm * 64 + mi * 16 + quad * 4 + reg;
        if (row < Mrows) atomicAdd(&outs[row], s);
      }
    }
  }
}

// ---------------- block reduce helper ----------------
__device__ __forceinline__ float block_reduce(float v, bool is_max, float* redbuf) {
#pragma unroll
  for (int off = 1; off < 64; off <<= 1) {
    float o = __shfl_xor(v, off);
    v = is_max ? fmaxf(v, o) : (v + o);
  }
  int wv = threadIdx.x >> 6;
  if ((threadIdx.x & 63) == 0) redbuf[wv] = v;
  __syncthreads();
  float r = is_max ? fmaxf(fmaxf(redbuf[0], redbuf[1]), fmaxf(redbuf[2], redbuf[3]))
                   : (redbuf[0] + redbuf[1] + redbuf[2] + redbuf[3]);
  __syncthreads();
  return r;
}

// ---------------- kernel 2: masked two-range softmax pooling ----------------
// grid (NPAIR, 8): blockIdx.y = l-chunk; float4 partial sums atomicAdd'ed into
// zero-initialized emb. Softmax weights recomputed redundantly per chunk (cheap).
__global__ __launch_bounds__(256) void k_pool(
    const float* __restrict__ X, const float* __restrict__ scores,
    const int* __restrict__ fsep, const int* __restrict__ ssep,
    float* __restrict__ emb, float* __restrict__ out) {
  const int p = blockIdx.x;
  const int c = blockIdx.y;
  const int t = threadIdx.x;
  const int fs = fsep[p], ss = ssep[p];
  __shared__ float sw1[LSEQ], sw2[LSEQ];
  __shared__ float redbuf[4];

  float m1p = -INFINITY, m2p = -INFINITY;
  for (int l = t; l < LSEQ; l += 256) {
    float s = scores[p * LSEQ + l];
    float s1 = (l >= 1 && l < fs) ? s : -INFINITY;
    float s2 = (l > fs && l < ss) ? s : -INFINITY;
    sw1[l] = s1;
    sw2[l] = s2;
    m1p = fmaxf(m1p, s1);
    m2p = fmaxf(m2p, s2);
  }
  __syncthreads();
  float m1 = block_reduce(m1p, true, redbuf);
  float m2 = block_reduce(m2p, true, redbuf);

  float d1p = 0.f, d2p = 0.f;
  for (int l = t; l < LSEQ; l += 256) {
    float e1v = __expf(sw1[l] - m1);
    float e2v = __expf(sw2[l] - m2);
    sw1[l] = e1v;
    sw2[l] = e2v;
    d1p += e1v;
    d2p += e2v;
  }
  __syncthreads();
  float inv1 = 1.f / block_reduce(d1p, false, redbuf);
  float inv2 = 1.f / block_reduce(d2p, false, redbuf);

  const float* base = X + (size_t)p * LSEQ * DDIM;

  if (c == 0) {  // pair_embeddings = all_output[:, 0, :] (exact copy)
    float* po = out + (size_t)p * DDIM;
    po[t] = base[t]; po[t + 256] = base[t + 256]; po[t + 512] = base[t + 512];
  }

  if (t < 192) {  // float4 lanes covering 768 cols
    float4 A1 = make_float4(0.f, 0.f, 0.f, 0.f);
    float4 A2 = make_float4(0.f, 0.f, 0.f, 0.f);
    for (int l = 1 + c; l < ss; l += 8) {
      float wa = sw1[l] * inv1, wb = sw2[l] * inv2;
      float4 x = *(const float4*)(base + (size_t)l * DDIM + 4 * t);
      A1.x += wa * x.x; A1.y += wa * x.y; A1.z += wa * x.z; A1.w += wa * x.w;
      A2.x += wb * x.x; A2.y += wb * x.y; A2.z += wb * x.z; A2.w += wb * x.w;
    }
    float* e1 = emb + (size_t)(2 * p) * DDIM + 4 * t;
    float* e2 = emb + (size_t)(2 * p + 1) * DDIM + 4 * t;
    atomicAdd(&e1[0], A1.x); atomicAdd(&e1[1], A1.y);
    atomicAdd(&e1[2], A1.z); atomicAdd(&e1[3], A1.w);
    atomicAdd(&e2[0], A2.x); atomicAdd(&e2[1], A2.y);
    atomicAdd(&e2[2], A2.z); atomicAdd(&e2[3], A2.w);
  }
}

// ---------------- kernel 3: segment softmax + weighted sum (direct enumeration) ----------------
__global__ __launch_bounds__(256) void k_segout(
    const float* __restrict__ emb, const float* __restrict__ sc,
    float* __restrict__ out2) {
  const int g = blockIdx.x;  // 0..31
  const int z = g >> 3, j = g & 7;
  const int t = threadIdx.x;
  int ee[14];
#pragma unroll
  for (int i = 0; i < 7; ++i) ee[i] = 2 * (z * 56 + j * 7 + i);  // slot-0 entries
#pragma unroll
  for (int i = 0; i < 7; ++i) {  // slot-1 entries: pairs (j2, j), j2 != j
    int j2 = i + (i >= j ? 1 : 0);
    int kk = j - (j > j2 ? 1 : 0);
    ee[7 + i] = 2 * (z * 56 + j2 * 7 + kk) + 1;
  }
  float sv[14];
  float m = -INFINITY;
#pragma unroll
  for (int i = 0; i < 14; ++i) { sv[i] = sc[ee[i]]; m = fmaxf(m, sv[i]); }
  float den = 0.f;
#pragma unroll
  for (int i = 0; i < 14; ++i) { sv[i] = __expf(sv[i] - m); den += sv[i]; }
  float inv = 1.f / den;
  float a0 = 0.f, a1 = 0.f, a2 = 0.f;
#pragma unroll
  for (int i = 0; i < 14; ++i) {
    float wgt = sv[i] * inv;
    const float* er = emb + (size_t)ee[i] * DDIM;
    a0 += wgt * er[t]; a1 += wgt * er[t + 256]; a2 += wgt * er[t + 512];
  }
  out2[(size_t)g * DDIM + t] = a0;
  out2[(size_t)g * DDIM + t + 256] = a1;
  out2[(size_t)g * DDIM + t + 512] = a2;
}

// ---------------- launcher ----------------
extern "C" void kernel_launch(void* const* d_in, const int* in_sizes, int n_in,
                              void* d_out, int out_size, void* d_ws, size_t ws_size,
                              hipStream_t stream) {
  const float* X  = (const float*)d_in[0];
  const int* fs   = (const int*)d_in[1];
  const int* ss   = (const int*)d_in[2];
  const float* W1 = (const float*)d_in[3];
  const float* b1 = (const float*)d_in[4];
  const float* v1 = (const float*)d_in[5];
  // d_in[6] = vb1: shift-invariant under softmax -> unused
  const float* W2 = (const float*)d_in[7];
  const float* b2 = (const float*)d_in[8];
  const float* v2 = (const float*)d_in[9];
  // d_in[10] = vb2: unused
  float* out = (float*)d_out;

  char* ws = (char*)d_ws;
  unsigned short* Wt = (unsigned short*)ws;  // 1,179,648 B (W1t, then W2t; GEMM A done before reuse)
  float* scores = (float*)(ws + 1179648);    // 313,600 B (reused as sc after k_pool)
  float* emb    = (float*)(ws + 1493248);    // 1,376,256 B
  float* sc     = scores;

  // Stage A: scores = tanh(X@W1+b1)@v1
  k_w1t<<<dim3(24, 24), 256, 0, stream>>>(W1, Wt);
  hipMemsetAsync(scores, 0, 78400 * sizeof(float), stream);
  hipMemsetAsync(emb, 0, 448 * DDIM * sizeof(float), stream);
  k_gemm_score<<<77 * 48, 256, 0, stream>>>(X, Wt, b1, v1, scores, MROWS1, 1);
  // Stage B: masked two-range softmax pooling (+ pair_embeddings copy)
  k_pool<<<dim3(NPAIR, 8), 256, 0, stream>>>(X, scores, fs, ss, emb, out);
  // Stage C: sc = tanh(emb@W2+b2)@v2 via the same MFMA kernel
  k_w1t<<<dim3(24, 24), 256, 0, stream>>>(W2, Wt);
  hipMemsetAsync(sc, 0, 448 * sizeof(float), stream);
  k_gemm_score<<<dim3(6, 4), 256, 0, stream>>>(emb, Wt, b2, v2, sc, 448, 0);
  // Stage D: segment softmax + weighted sum
  k_segout<<<32, 256, 0, stream>>>(emb, sc, out + (size_t)NPAIR * DDIM);
}

// Round 4
// 546.720 us; speedup vs baseline: 1.2780x; 1.2780x over previous
//
#include <hip/hip_runtime.h>
#include <math.h>

#define LSEQ   350
#define DDIM   768
#define NPAIR  224
#define MROWS1 78400
#define NSLAB1 613   // ceil(78400/128) (fallback path)

typedef short bf16x8 __attribute__((ext_vector_type(8)));
typedef float f32x4  __attribute__((ext_vector_type(4)));

typedef const unsigned int __attribute__((address_space(1)))* gas_ptr;
typedef unsigned int __attribute__((address_space(3)))* las_ptr;

__device__ __forceinline__ void gload_lds16(const void* g, void* l) {
  __builtin_amdgcn_global_load_lds((gas_ptr)g, (las_ptr)l, 16, 0, 0);
}

__device__ __forceinline__ unsigned short f2bf(float x) {
  unsigned int u = __float_as_uint(x);
  unsigned int r = (u + 0x7FFFu + ((u >> 16) & 1u)) >> 16;  // RNE
  return (unsigned short)r;
}

__device__ __forceinline__ float tanh_fast(float x) {
  float e = __expf(2.f * x);
  return 1.f - 2.f / (e + 1.f);
}

// ---------------- kernel 0: W -> Wt (transposed, bf16) ----------------
__global__ __launch_bounds__(256) void k_w1t(const float* __restrict__ W,
                                             unsigned short* __restrict__ Wt) {
  __shared__ float tile[32][33];
  int bk = blockIdx.x * 32, bn = blockIdx.y * 32;
  int tx = threadIdx.x & 31, ty = threadIdx.x >> 5;
#pragma unroll
  for (int i = 0; i < 32; i += 8)
    tile[ty + i][tx] = W[(size_t)(bk + ty + i) * DDIM + bn + tx];
  __syncthreads();
#pragma unroll
  for (int i = 0; i < 32; i += 8)
    Wt[(size_t)(bn + ty + i) * DDIM + bk + tx] = f2bf(tile[tx][ty + i]);
}

// ---------------- kernel: X -> Xbf (bf16), per-pair tiles, culled ----------------
// grid (NPAIR, 3, 4): converts tile rows [tile*128, tile*128+128) of pair p
// (z = quarter of the tile). Skips tiles with tile*128 >= ss[p] (rows never read).
__global__ __launch_bounds__(256) void k_conv(const float* __restrict__ X,
                                              const int* __restrict__ ssep,
                                              unsigned short* __restrict__ Xbf) {
  const int p = blockIdx.x, tile = blockIdx.y, z = blockIdx.z;
  if (tile * 128 >= ssep[p]) return;
  const int t = threadIdx.x;
  // flat float4 index base for this block's 32 rows
  const size_t base4 = ((size_t)p * LSEQ + tile * 128 + z * 32) * (DDIM / 4);
  const size_t limit4 = (size_t)MROWS1 * (DDIM / 4);
  const float4* X4 = (const float4*)X;
  uint2* O2 = (uint2*)Xbf;
#pragma unroll
  for (int k = 0; k < 24; ++k) {
    size_t i4 = base4 + (size_t)k * 256 + t;
    if (i4 >= limit4) break;
    float4 x = X4[i4];
    unsigned int ux = __float_as_uint(x.x) + 0x8000u;
    unsigned int uy = __float_as_uint(x.y) + 0x8000u;
    unsigned int uz = __float_as_uint(x.z) + 0x8000u;
    unsigned int uw = __float_as_uint(x.w) + 0x8000u;
    O2[i4] = make_uint2(__builtin_amdgcn_perm(uy, ux, 0x07060302u),
                        __builtin_amdgcn_perm(uw, uz, 0x07060302u));
  }
}

// ---------------- kernel: bf16 GEMM + tanh-dot epilogue, per-pair tiles ----------------
// grid = 84*48 (=4032). decode: g=b/48, r=b%48; unit=g*8+(r&7) in [0,672),
// nchunk=r>>3. unit -> (pair, tile). The 6 nchunks of one unit run consecutively
// on the SAME XCD (round-robin %8) -> A-slab reused from that XCD's L2.
// m97 structure: global_load_lds width 16 for A and B, unpadded 128x32 LDS tiles.
__global__ __launch_bounds__(256, 4) void k_gemm_bf16(
    const unsigned short* __restrict__ Xbf, const unsigned short* __restrict__ Wt,
    const float* __restrict__ bias, const float* __restrict__ vv,
    const int* __restrict__ ssep, float* __restrict__ outs) {
  const int b = blockIdx.x;
  const int g = b / 48, r = b - g * 48;
  const int unit = g * 8 + (r & 7);
  const int nchunk = r >> 3;
  const int pair = unit / 3, tile = unit - pair * 3;
  if (tile * 128 >= ssep[pair]) return;  // uniform, before any barrier

  const size_t arow0 = (size_t)pair * LSEQ + tile * 128;
  const int n0 = nchunk * 128;

  __shared__ unsigned short As[128 * 32];
  __shared__ unsigned short Bs[128 * 32];

  const int t = threadIdx.x;
  const int lane = t & 63, w = t >> 6;
  const int l15 = t & 15;
  const int quad = (t >> 4) & 3;
  const int wm = w >> 1, wn = w & 1;
  const int lrow = lane >> 2;          // DMA: row within 16-row segment
  const int lcol = (lane & 3) * 8;     // DMA: k offset (8 bf16 = 16 B)

  f32x4 acc[4][4];
#pragma unroll
  for (int mi = 0; mi < 4; ++mi)
#pragma unroll
    for (int ni = 0; ni < 4; ++ni)
#pragma unroll
      for (int q = 0; q < 4; ++q) acc[mi][ni][q] = 0.f;

  for (int k0 = 0; k0 < DDIM; k0 += 32) {
    // async DMA: each wave stages 2 A-segments + 2 B-segments (16 rows x 32 k each)
#pragma unroll
    for (int j = 0; j < 2; ++j) {
      int seg = w * 2 + j;
      gload_lds16(Xbf + (arow0 + seg * 16 + lrow) * DDIM + k0 + lcol, As + seg * 512);
      gload_lds16(Wt + (size_t)(n0 + seg * 16 + lrow) * DDIM + k0 + lcol, Bs + seg * 512);
    }
    __syncthreads();  // drains vmcnt before barrier

    bf16x8 a[4], bfr[4];
#pragma unroll
    for (int mi = 0; mi < 4; ++mi)
      a[mi] = *(const bf16x8*)&As[(wm * 64 + mi * 16 + l15) * 32 + quad * 8];
#pragma unroll
    for (int ni = 0; ni < 4; ++ni)
      bfr[ni] = *(const bf16x8*)&Bs[(wn * 64 + ni * 16 + l15) * 32 + quad * 8];
#pragma unroll
    for (int mi = 0; mi < 4; ++mi)
#pragma unroll
      for (int ni = 0; ni < 4; ++ni)
        acc[mi][ni] = __builtin_amdgcn_mfma_f32_16x16x32_bf16(a[mi], bfr[ni], acc[mi][ni], 0, 0, 0);
    __syncthreads();
  }

  // epilogue: tanh + dot vv over this block's 128 n-cols, shuffle-reduce, atomic
  float vvv[4], bbv[4];
#pragma unroll
  for (int ni = 0; ni < 4; ++ni) {
    int n = n0 + wn * 64 + ni * 16 + l15;
    vvv[ni] = vv[n];
    bbv[ni] = bias[n];
  }
#pragma unroll
  for (int mi = 0; mi < 4; ++mi) {
#pragma unroll
    for (int reg = 0; reg < 4; ++reg) {
      float s = 0.f;
#pragma unroll
      for (int ni = 0; ni < 4; ++ni)
        s += tanh_fast(acc[mi][ni][reg] + bbv[ni]) * vvv[ni];
      s += __shfl_xor(s, 1);
      s += __shfl_xor(s, 2);
      s += __shfl_xor(s, 4);
      s += __shfl_xor(s, 8);
      if (l15 == mi * 4 + reg) {
        int l = tile * 128 + wm * 64 + mi * 16 + quad * 4 + reg;
        if (l < LSEQ) atomicAdd(&outs[pair * LSEQ + l], s);
      }
    }
  }
}

// ---------------- fallback big GEMM (R3): fused fp32->bf16 staging ----------------
__global__ __launch_bounds__(256, 2) void k_gemm_score(
    const float* __restrict__ X, const unsigned short* __restrict__ Wt,
    const float* __restrict__ bias, const float* __restrict__ vv,
    float* __restrict__ outs, int Mrows, int swz) {
  int slab, nchunk;
  if (swz) {
    int b = blockIdx.x;
    int g = b / 48, r = b - g * 48;
    slab = g * 8 + (r & 7);
    nchunk = r >> 3;
    if (slab >= NSLAB1) return;
  } else {
    slab = blockIdx.y;
    nchunk = blockIdx.x;
  }
  const int row0 = slab * 128;
  const int n0 = nchunk * 128;

  __shared__ unsigned short As[128][40];
  __shared__ unsigned short Bs[128][40];

  const int t = threadIdx.x;
  const int l15 = t & 15;
  const int quad = (t >> 4) & 3;
  const int w = t >> 6;
  const int wm = w >> 1, wn = w & 1;
  const int ar = t >> 3;
  const int ac = (t & 7) * 4;
  const int br = t >> 2;
  const int bc = (t & 3) * 8;

  f32x4 acc[4][4];
#pragma unroll
  for (int mi = 0; mi < 4; ++mi)
#pragma unroll
    for (int ni = 0; ni < 4; ++ni)
#pragma unroll
      for (int q = 0; q < 4; ++q) acc[mi][ni][q] = 0.f;

  for (int k0 = 0; k0 < DDIM; k0 += 32) {
#pragma unroll
    for (int pass = 0; pass < 4; ++pass) {
      int rr = ar + pass * 32;
      int row = row0 + rr;
      float4 x = make_float4(0.f, 0.f, 0.f, 0.f);
      if (row < Mrows) x = *(const float4*)(X + (size_t)row * DDIM + k0 + ac);
      unsigned int ux = __float_as_uint(x.x) + 0x8000u;
      unsigned int uy = __float_as_uint(x.y) + 0x8000u;
      unsigned int uz = __float_as_uint(x.z) + 0x8000u;
      unsigned int uw = __float_as_uint(x.w) + 0x8000u;
      *(uint2*)&As[rr][ac] = make_uint2(__builtin_amdgcn_perm(uy, ux, 0x07060302u),
                                        __builtin_amdgcn_perm(uw, uz, 0x07060302u));
    }
#pragma unroll
    for (int pp = 0; pp < 2; ++pp) {
      int rr = br + pp * 64;
      *(uint4*)&Bs[rr][bc] = *(const uint4*)(Wt + (size_t)(n0 + rr) * DDIM + k0 + bc);
    }
    __syncthreads();

    bf16x8 a[4], bfr[4];
#pragma unroll
    for (int mi = 0; mi < 4; ++mi)
      a[mi] = *(const bf16x8*)&As[wm * 64 + mi * 16 + l15][quad * 8];
#pragma unroll
    for (int ni = 0; ni < 4; ++ni)
      bfr[ni] = *(const bf16x8*)&Bs[wn * 64 + ni * 16 + l15][quad * 8];
#pragma unroll
    for (int mi = 0; mi < 4; ++mi)
#pragma unroll
      for (int ni = 0; ni < 4; ++ni)
        acc[mi][ni] = __builtin_amdgcn_mfma_f32_16x16x32_bf16(a[mi], bfr[ni], acc[mi][ni], 0, 0, 0);
    __syncthreads();
  }

  float vvv[4], bbv[4];
#pragma unroll
  for (int ni = 0; ni < 4; ++ni) {
    int n = n0 + wn * 64 + ni * 16 + l15;
    vvv[ni] = vv[n];
    bbv[ni] = bias[n];
  }
#pragma unroll
  for (int mi = 0; mi < 4; ++mi) {
#pragma unroll
    for (int reg = 0; reg < 4; ++reg) {
      float s = 0.f;
#pragma unroll
      for (int ni = 0; ni < 4; ++ni)
        s += tanh_fast(acc[mi][ni][reg] + bbv[ni]) * vvv[ni];
      s += __shfl_xor(s, 1);
      s += __shfl_xor(s, 2);
      s += __shfl_xor(s, 4);
      s += __shfl_xor(s, 8);
      if (l15 == mi * 4 + reg) {
        int row = row0 + wm * 64 + mi * 16 + quad * 4 + reg;
        if (row < Mrows) atomicAdd(&outs[row], s);
      }
    }
  }
}

// ---------------- block reduce helper ----------------
__device__ __forceinline__ float block_reduce(float v, bool is_max, float* redbuf) {
#pragma unroll
  for (int off = 1; off < 64; off <<= 1) {
    float o = __shfl_xor(v, off);
    v = is_max ? fmaxf(v, o) : (v + o);
  }
  int wv = threadIdx.x >> 6;
  if ((threadIdx.x & 63) == 0) redbuf[wv] = v;
  __syncthreads();
  float r = is_max ? fmaxf(fmaxf(redbuf[0], redbuf[1]), fmaxf(redbuf[2], redbuf[3]))
                   : (redbuf[0] + redbuf[1] + redbuf[2] + redbuf[3]);
  __syncthreads();
  return r;
}

// ---------------- kernel: per-pair softmax weights (computed ONCE) ----------------
__global__ __launch_bounds__(256) void k_smax(
    const float* __restrict__ scores, const int* __restrict__ fsep,
    const int* __restrict__ ssep, float* __restrict__ w1n, float* __restrict__ w2n) {
  const int p = blockIdx.x, t = threadIdx.x;
  const int fs = fsep[p], ss = ssep[p];
  __shared__ float redbuf[4];
  float s1a[2], s2a[2];
  float m1p = -INFINITY, m2p = -INFINITY;
#pragma unroll
  for (int i = 0; i < 2; ++i) {
    int l = t + i * 256;
    float s1 = -INFINITY, s2 = -INFINITY;
    if (l < LSEQ) {
      float s = scores[p * LSEQ + l];
      s1 = (l >= 1 && l < fs) ? s : -INFINITY;
      s2 = (l > fs && l < ss) ? s : -INFINITY;
    }
    s1a[i] = s1; s2a[i] = s2;
    m1p = fmaxf(m1p, s1); m2p = fmaxf(m2p, s2);
  }
  float m1 = block_reduce(m1p, true, redbuf);
  float m2 = block_reduce(m2p, true, redbuf);
  float d1p = 0.f, d2p = 0.f;
#pragma unroll
  for (int i = 0; i < 2; ++i) {
    s1a[i] = __expf(s1a[i] - m1);   // exp(-inf - finite) = 0
    s2a[i] = __expf(s2a[i] - m2);
    d1p += s1a[i]; d2p += s2a[i];
  }
  float inv1 = 1.f / block_reduce(d1p, false, redbuf);
  float inv2 = 1.f / block_reduce(d2p, false, redbuf);
#pragma unroll
  for (int i = 0; i < 2; ++i) {
    int l = t + i * 256;
    if (l < LSEQ) {
      w1n[p * LSEQ + l] = s1a[i] * inv1;
      w2n[p * LSEQ + l] = s2a[i] * inv2;
    }
  }
}

// ---------------- kernel: streaming weighted pooling from bf16 X ----------------
// grid (NPAIR, 8), block 192. Pure weighted sum; weights precomputed by k_smax.
__global__ __launch_bounds__(192) void k_pool_bf(
    const unsigned short* __restrict__ Xbf, const float* __restrict__ X,
    const float* __restrict__ w1n, const float* __restrict__ w2n,
    const int* __restrict__ ssep, float* __restrict__ emb, float* __restrict__ out) {
  const int p = blockIdx.x, c = blockIdx.y, t = threadIdx.x;
  const int ss = ssep[p];
  const size_t prow = (size_t)p * LSEQ;
  float A1[4] = {0.f, 0.f, 0.f, 0.f}, A2[4] = {0.f, 0.f, 0.f, 0.f};
  for (int l = 1 + c; l < ss; l += 8) {
    float wa = w1n[prow + l], wb = w2n[prow + l];
    uint2 xv = *(const uint2*)(Xbf + (prow + l) * DDIM + t * 4);
    float x0 = __uint_as_float((xv.x & 0xFFFFu) << 16);
    float x1 = __uint_as_float(xv.x & 0xFFFF0000u);
    float x2 = __uint_as_float((xv.y & 0xFFFFu) << 16);
    float x3 = __uint_as_float(xv.y & 0xFFFF0000u);
    A1[0] += wa * x0; A1[1] += wa * x1; A1[2] += wa * x2; A1[3] += wa * x3;
    A2[0] += wb * x0; A2[1] += wb * x1; A2[2] += wb * x2; A2[3] += wb * x3;
  }
  float* e1 = emb + (size_t)(2 * p) * DDIM + t * 4;
  float* e2 = emb + (size_t)(2 * p + 1) * DDIM + t * 4;
#pragma unroll
  for (int i = 0; i < 4; ++i) atomicAdd(&e1[i], A1[i]);
#pragma unroll
  for (int i = 0; i < 4; ++i) atomicAdd(&e2[i], A2[i]);
  if (c == 0) {  // pair_embeddings = all_output[:, 0, :] (exact fp32 copy)
    *(float4*)(out + (size_t)p * DDIM + t * 4) = *(const float4*)(X + prow * DDIM + t * 4);
  }
}

// ---------------- fallback pooling (R3) ----------------
__global__ __launch_bounds__(256) void k_pool(
    const float* __restrict__ X, const float* __restrict__ scores,
    const int* __restrict__ fsep, const int* __restrict__ ssep,
    float* __restrict__ emb, float* __restrict__ out) {
  const int p = blockIdx.x;
  const int c = blockIdx.y;
  const int t = threadIdx.x;
  const int fs = fsep[p], ss = ssep[p];
  __shared__ float sw1[LSEQ], sw2[LSEQ];
  __shared__ float redbuf[4];

  float m1p = -INFINITY, m2p = -INFINITY;
  for (int l = t; l < LSEQ; l += 256) {
    float s = scores[p * LSEQ + l];
    float s1 = (l >= 1 && l < fs) ? s : -INFINITY;
    float s2 = (l > fs && l < ss) ? s : -INFINITY;
    sw1[l] = s1; sw2[l] = s2;
    m1p = fmaxf(m1p, s1); m2p = fmaxf(m2p, s2);
  }
  __syncthreads();
  float m1 = block_reduce(m1p, true, redbuf);
  float m2 = block_reduce(m2p, true, redbuf);
  float d1p = 0.f, d2p = 0.f;
  for (int l = t; l < LSEQ; l += 256) {
    float e1v = __expf(sw1[l] - m1);
    float e2v = __expf(sw2[l] - m2);
    sw1[l] = e1v; sw2[l] = e2v;
    d1p += e1v; d2p += e2v;
  }
  __syncthreads();
  float inv1 = 1.f / block_reduce(d1p, false, redbuf);
  float inv2 = 1.f / block_reduce(d2p, false, redbuf);
  const float* base = X + (size_t)p * LSEQ * DDIM;
  if (c == 0) {
    float* po = out + (size_t)p * DDIM;
    po[t] = base[t]; po[t + 256] = base[t + 256]; po[t + 512] = base[t + 512];
  }
  if (t < 192) {
    float4 A1 = make_float4(0.f, 0.f, 0.f, 0.f);
    float4 A2 = make_float4(0.f, 0.f, 0.f, 0.f);
    for (int l = 1 + c; l < ss; l += 8) {
      float wa = sw1[l] * inv1, wb = sw2[l] * inv2;
      float4 x = *(const float4*)(base + (size_t)l * DDIM + 4 * t);
      A1.x += wa * x.x; A1.y += wa * x.y; A1.z += wa * x.z; A1.w += wa * x.w;
      A2.x += wb * x.x; A2.y += wb * x.y; A2.z += wb * x.z; A2.w += wb * x.w;
    }
    float* e1 = emb + (size_t)(2 * p) * DDIM + 4 * t;
    float* e2 = emb + (size_t)(2 * p + 1) * DDIM + 4 * t;
    atomicAdd(&e1[0], A1.x); atomicAdd(&e1[1], A1.y);
    atomicAdd(&e1[2], A1.z); atomicAdd(&e1[3], A1.w);
    atomicAdd(&e2[0], A2.x); atomicAdd(&e2[1], A2.y);
    atomicAdd(&e2[2], A2.z); atomicAdd(&e2[3], A2.w);
  }
}

// ---------------- kernel: segment softmax + weighted sum ----------------
__global__ __launch_bounds__(256) void k_segout(
    const float* __restrict__ emb, const float* __restrict__ sc,
    float* __restrict__ out2) {
  const int g = blockIdx.x;  // 0..31
  const int z = g >> 3, j = g & 7;
  const int t = threadIdx.x;
  int ee[14];
#pragma unroll
  for (int i = 0; i < 7; ++i) ee[i] = 2 * (z * 56 + j * 7 + i);
#pragma unroll
  for (int i = 0; i < 7; ++i) {
    int j2 = i + (i >= j ? 1 : 0);
    int kk = j - (j > j2 ? 1 : 0);
    ee[7 + i] = 2 * (z * 56 + j2 * 7 + kk) + 1;
  }
  float sv[14];
  float m = -INFINITY;
#pragma unroll
  for (int i = 0; i < 14; ++i) { sv[i] = sc[ee[i]]; m = fmaxf(m, sv[i]); }
  float den = 0.f;
#pragma unroll
  for (int i = 0; i < 14; ++i) { sv[i] = __expf(sv[i] - m); den += sv[i]; }
  float inv = 1.f / den;
  float a0 = 0.f, a1 = 0.f, a2 = 0.f;
#pragma unroll
  for (int i = 0; i < 14; ++i) {
    float wgt = sv[i] * inv;
    const float* er = emb + (size_t)ee[i] * DDIM;
    a0 += wgt * er[t]; a1 += wgt * er[t + 256]; a2 += wgt * er[t + 512];
  }
  out2[(size_t)g * DDIM + t] = a0;
  out2[(size_t)g * DDIM + t + 256] = a1;
  out2[(size_t)g * DDIM + t + 512] = a2;
}

// ---------------- launcher ----------------
extern "C" void kernel_launch(void* const* d_in, const int* in_sizes, int n_in,
                              void* d_out, int out_size, void* d_ws, size_t ws_size,
                              hipStream_t stream) {
  const float* X  = (const float*)d_in[0];
  const int* fs   = (const int*)d_in[1];
  const int* ss   = (const int*)d_in[2];
  const float* W1 = (const float*)d_in[3];
  const float* b1 = (const float*)d_in[4];
  const float* v1 = (const float*)d_in[5];
  const float* W2 = (const float*)d_in[7];
  const float* b2 = (const float*)d_in[8];
  const float* v2 = (const float*)d_in[9];
  float* out = (float*)d_out;

  char* ws = (char*)d_ws;
  // fast-path layout
  const size_t XBF_BYTES = (size_t)78464 * DDIM * 2;  // 78400 + 64 pad rows = 120,520,704
  const size_t OFF_WT  = XBF_BYTES;
  const size_t OFF_SC  = OFF_WT + 1179648;
  const size_t OFF_EMB = OFF_SC + 313600;
  const size_t OFF_W1N = OFF_EMB + 1376256;
  const size_t OFF_W2N = OFF_W1N + 313600;
  const size_t NEED    = OFF_W2N + 313600;  // ~124 MB

  if (ws_size >= NEED) {
    unsigned short* Xbf = (unsigned short*)ws;
    unsigned short* Wt  = (unsigned short*)(ws + OFF_WT);
    float* scores = (float*)(ws + OFF_SC);
    float* emb    = (float*)(ws + OFF_EMB);
    float* w1n    = (float*)(ws + OFF_W1N);
    float* w2n    = (float*)(ws + OFF_W2N);
    float* sc     = scores;  // alias: scores dead after k_smax

    k_w1t<<<dim3(24, 24), 256, 0, stream>>>(W1, Wt);
    hipMemsetAsync(scores, 0, MROWS1 * sizeof(float), stream);
    hipMemsetAsync(emb, 0, 448 * DDIM * sizeof(float), stream);
    k_conv<<<dim3(NPAIR, 3, 4), 256, 0, stream>>>(X, ss, Xbf);
    k_gemm_bf16<<<84 * 48, 256, 0, stream>>>(Xbf, Wt, b1, v1, ss, scores);
    k_smax<<<NPAIR, 256, 0, stream>>>(scores, fs, ss, w1n, w2n);
    k_pool_bf<<<dim3(NPAIR, 8), 192, 0, stream>>>(Xbf, X, w1n, w2n, ss, emb, out);
    k_w1t<<<dim3(24, 24), 256, 0, stream>>>(W2, Wt);
    hipMemsetAsync(sc, 0, 448 * sizeof(float), stream);
    k_gemm_score<<<dim3(6, 4), 256, 0, stream>>>(emb, Wt, b2, v2, sc, 448, 0);
    k_segout<<<32, 256, 0, stream>>>(emb, sc, out + (size_t)NPAIR * DDIM);
  } else {
    // fallback (R3 path, ~2.9 MB ws)
    unsigned short* Wt = (unsigned short*)ws;
    float* scores = (float*)(ws + 1179648);
    float* emb    = (float*)(ws + 1493248);
    float* sc     = scores;

    k_w1t<<<dim3(24, 24), 256, 0, stream>>>(W1, Wt);
    hipMemsetAsync(scores, 0, MROWS1 * sizeof(float), stream);
    hipMemsetAsync(emb, 0, 448 * DDIM * sizeof(float), stream);
    k_gemm_score<<<77 * 48, 256, 0, stream>>>(X, Wt, b1, v1, scores, MROWS1, 1);
    k_pool<<<dim3(NPAIR, 8), 256, 0, stream>>>(X, scores, fs, ss, emb, out);
    k_w1t<<<dim3(24, 24), 256, 0, stream>>>(W2, Wt);
    hipMemsetAsync(sc, 0, 448 * sizeof(float), stream);
    k_gemm_score<<<dim3(6, 4), 256, 0, stream>>>(emb, Wt, b2, v2, sc, 448, 0);
    k_segout<<<32, 256, 0, stream>>>(emb, sc, out + (size_t)NPAIR * DDIM);
  }
}

// Round 5
// 500.002 us; speedup vs baseline: 1.3974x; 1.0934x over previous
//
#include <hip/hip_runtime.h>
#include <math.h>

#define LSEQ   350
#define DDIM   768
#define NPAIR  224
#define MROWS1 78400
#define NSLAB1 613      // fallback path
#define MAXSLAB 520     // ceil(224*297/128) worst-case compacted slabs

typedef short bf16x8 __attribute__((ext_vector_type(8)));
typedef float f32x4  __attribute__((ext_vector_type(4)));

typedef const unsigned int __attribute__((address_space(1)))* gas_ptr;
typedef unsigned int __attribute__((address_space(3)))* las_ptr;

__device__ __forceinline__ void gload_lds16(const void* g, void* l) {
  __builtin_amdgcn_global_load_lds((gas_ptr)g, (las_ptr)l, 16, 0, 0);
}

__device__ __forceinline__ unsigned short f2bf(float x) {
  unsigned int u = __float_as_uint(x);
  unsigned int r = (u + 0x7FFFu + ((u >> 16) & 1u)) >> 16;  // RNE
  return (unsigned short)r;
}

__device__ __forceinline__ float tanh_fast(float x) {
  float e = __expf(2.f * x);
  return 1.f - 2.f / (e + 1.f);
}

// ---------------- kernel: exclusive prefix scan of (ss[p]-1) ----------------
__global__ __launch_bounds__(256) void k_scan(const int* __restrict__ ssep,
                                              int* __restrict__ off) {
  __shared__ int buf[256];
  const int t = threadIdx.x;
  int v = (t < NPAIR) ? (ssep[t] - 1) : 0;
  buf[t] = v;
  __syncthreads();
#pragma unroll
  for (int d = 1; d < 256; d <<= 1) {
    int add = (t >= d) ? buf[t - d] : 0;
    __syncthreads();
    buf[t] += add;
    __syncthreads();
  }
  if (t < NPAIR) off[t] = buf[t] - v;          // exclusive
  if (t == NPAIR - 1) off[NPAIR] = buf[t];     // total compacted rows
}

// ---------------- kernel: W1,W2 -> Wt1,Wt2 (transposed, bf16) ----------------
__global__ __launch_bounds__(256) void k_wt2(const float* __restrict__ W1,
                                             const float* __restrict__ W2,
                                             unsigned short* __restrict__ Wt1,
                                             unsigned short* __restrict__ Wt2) {
  const float* W = blockIdx.z ? W2 : W1;
  unsigned short* Wt = blockIdx.z ? Wt2 : Wt1;
  __shared__ float tile[32][33];
  int bk = blockIdx.x * 32, bn = blockIdx.y * 32;
  int tx = threadIdx.x & 31, ty = threadIdx.x >> 5;
#pragma unroll
  for (int i = 0; i < 32; i += 8)
    tile[ty + i][tx] = W[(size_t)(bk + ty + i) * DDIM + bn + tx];
  __syncthreads();
#pragma unroll
  for (int i = 0; i < 32; i += 8)
    Wt[(size_t)(bn + ty + i) * DDIM + bk + tx] = f2bf(tile[tx][ty + i]);
}

// single-matrix version (fallback path)
__global__ __launch_bounds__(256) void k_w1t(const float* __restrict__ W,
                                             unsigned short* __restrict__ Wt) {
  __shared__ float tile[32][33];
  int bk = blockIdx.x * 32, bn = blockIdx.y * 32;
  int tx = threadIdx.x & 31, ty = threadIdx.x >> 5;
#pragma unroll
  for (int i = 0; i < 32; i += 8)
    tile[ty + i][tx] = W[(size_t)(bk + ty + i) * DDIM + bn + tx];
  __syncthreads();
#pragma unroll
  for (int i = 0; i < 32; i += 8)
    Wt[(size_t)(bn + ty + i) * DDIM + bk + tx] = f2bf(tile[tx][ty + i]);
}

// ---------------- kernel: X -> compacted Xbf (bf16) + rowmap ----------------
// grid (NPAIR, 3, 4). Pair p contributes rows l=1..ss[p]-1 at Xbf[off[p] + l-1].
// rowmap[compacted_row] = p*LSEQ + l (scatter target for the GEMM epilogue).
__global__ __launch_bounds__(256) void k_conv(const float* __restrict__ X,
                                              const int* __restrict__ ssep,
                                              const int* __restrict__ off,
                                              unsigned short* __restrict__ Xbf,
                                              int* __restrict__ rowmap) {
  const int p = blockIdx.x, tile = blockIdx.y, z = blockIdx.z;
  const int nrow = ssep[p] - 1;
  const int r0 = tile * 128 + z * 32;
  if (r0 >= nrow) return;
  const int t = threadIdx.x;
  const int o = off[p];
  if (t < 192) {
    for (int i = 0; i < 32; ++i) {
      int r = r0 + i;
      if (r >= nrow) break;
      float4 x = *(const float4*)(X + ((size_t)p * LSEQ + 1 + r) * DDIM + t * 4);
      unsigned int ux = __float_as_uint(x.x) + 0x8000u;
      unsigned int uy = __float_as_uint(x.y) + 0x8000u;
      unsigned int uz = __float_as_uint(x.z) + 0x8000u;
      unsigned int uw = __float_as_uint(x.w) + 0x8000u;
      *(uint2*)(Xbf + (size_t)(o + r) * DDIM + t * 4) =
          make_uint2(__builtin_amdgcn_perm(uy, ux, 0x07060302u),
                     __builtin_amdgcn_perm(uw, uz, 0x07060302u));
    }
  } else if (t < 224) {
    int r = r0 + (t - 192);
    if (r < nrow) rowmap[o + r] = p * LSEQ + 1 + r;
  }
}

// ---------------- kernel: compacted bf16 GEMM + tanh-dot epilogue ----------------
// grid = 65*48 (=3120). decode: g=b/48, r=b%48; slab=g*8+(r&7), nchunk=r>>3.
// The 6 nchunks of one slab run consecutively on the SAME XCD (round-robin %8)
// -> A-slab (196 KB) reused from that XCD's L2. m97 structure: global_load_lds
// width 16 for A and B, unpadded 128x32 LDS tiles.
__global__ __launch_bounds__(256, 4) void k_gemm_c(
    const unsigned short* __restrict__ Xbf, const unsigned short* __restrict__ Wt,
    const float* __restrict__ bias, const float* __restrict__ vv,
    const int* __restrict__ off, const int* __restrict__ rowmap,
    float* __restrict__ scores) {
  const int Mtotal = off[NPAIR];
  const int b = blockIdx.x;
  const int g = b / 48, r = b - g * 48;
  const int slab = g * 8 + (r & 7);
  const int nchunk = r >> 3;
  if (slab * 128 >= Mtotal) return;  // uniform, before any barrier

  const size_t arow0 = (size_t)slab * 128;
  const int n0 = nchunk * 128;

  __shared__ unsigned short As[128 * 32];
  __shared__ unsigned short Bs[128 * 32];

  const int t = threadIdx.x;
  const int lane = t & 63, w = t >> 6;
  const int l15 = t & 15;
  const int quad = (t >> 4) & 3;
  const int wm = w >> 1, wn = w & 1;
  const int lrow = lane >> 2;       // DMA: row within 16-row segment
  const int lcol = (lane & 3) * 8;  // DMA: k offset (8 bf16 = 16 B)

  f32x4 acc[4][4];
#pragma unroll
  for (int mi = 0; mi < 4; ++mi)
#pragma unroll
    for (int ni = 0; ni < 4; ++ni)
#pragma unroll
      for (int q = 0; q < 4; ++q) acc[mi][ni][q] = 0.f;

  for (int k0 = 0; k0 < DDIM; k0 += 32) {
#pragma unroll
    for (int j = 0; j < 2; ++j) {
      int seg = w * 2 + j;
      gload_lds16(Xbf + (arow0 + seg * 16 + lrow) * DDIM + k0 + lcol, As + seg * 512);
      gload_lds16(Wt + (size_t)(n0 + seg * 16 + lrow) * DDIM + k0 + lcol, Bs + seg * 512);
    }
    __syncthreads();

    bf16x8 a[4], bfr[4];
#pragma unroll
    for (int mi = 0; mi < 4; ++mi)
      a[mi] = *(const bf16x8*)&As[(wm * 64 + mi * 16 + l15) * 32 + quad * 8];
#pragma unroll
    for (int ni = 0; ni < 4; ++ni)
      bfr[ni] = *(const bf16x8*)&Bs[(wn * 64 + ni * 16 + l15) * 32 + quad * 8];
#pragma unroll
    for (int mi = 0; mi < 4; ++mi)
#pragma unroll
      for (int ni = 0; ni < 4; ++ni)
        acc[mi][ni] = __builtin_amdgcn_mfma_f32_16x16x32_bf16(a[mi], bfr[ni], acc[mi][ni], 0, 0, 0);
    __syncthreads();
  }

  float vvv[4], bbv[4];
#pragma unroll
  for (int ni = 0; ni < 4; ++ni) {
    int n = n0 + wn * 64 + ni * 16 + l15;
    vvv[ni] = vv[n];
    bbv[ni] = bias[n];
  }
#pragma unroll
  for (int mi = 0; mi < 4; ++mi) {
#pragma unroll
    for (int reg = 0; reg < 4; ++reg) {
      float s = 0.f;
#pragma unroll
      for (int ni = 0; ni < 4; ++ni)
        s += tanh_fast(acc[mi][ni][reg] + bbv[ni]) * vvv[ni];
      s += __shfl_xor(s, 1);
      s += __shfl_xor(s, 2);
      s += __shfl_xor(s, 4);
      s += __shfl_xor(s, 8);
      if (l15 == mi * 4 + reg) {
        int row = (int)arow0 + wm * 64 + mi * 16 + quad * 4 + reg;
        if (row < Mtotal) atomicAdd(&scores[rowmap[row]], s);
      }
    }
  }
}

// ---------------- fallback big GEMM (R3): fused fp32->bf16 staging ----------------
__global__ __launch_bounds__(256, 2) void k_gemm_score(
    const float* __restrict__ X, const unsigned short* __restrict__ Wt,
    const float* __restrict__ bias, const float* __restrict__ vv,
    float* __restrict__ outs, int Mrows, int swz) {
  int slab, nchunk;
  if (swz) {
    int b = blockIdx.x;
    int g = b / 48, r = b - g * 48;
    slab = g * 8 + (r & 7);
    nchunk = r >> 3;
    if (slab >= NSLAB1) return;
  } else {
    slab = blockIdx.y;
    nchunk = blockIdx.x;
  }
  const int row0 = slab * 128;
  const int n0 = nchunk * 128;

  __shared__ unsigned short As[128][40];
  __shared__ unsigned short Bs[128][40];

  const int t = threadIdx.x;
  const int l15 = t & 15;
  const int quad = (t >> 4) & 3;
  const int w = t >> 6;
  const int wm = w >> 1, wn = w & 1;
  const int ar = t >> 3;
  const int ac = (t & 7) * 4;
  const int br = t >> 2;
  const int bc = (t & 3) * 8;

  f32x4 acc[4][4];
#pragma unroll
  for (int mi = 0; mi < 4; ++mi)
#pragma unroll
    for (int ni = 0; ni < 4; ++ni)
#pragma unroll
      for (int q = 0; q < 4; ++q) acc[mi][ni][q] = 0.f;

  for (int k0 = 0; k0 < DDIM; k0 += 32) {
#pragma unroll
    for (int pass = 0; pass < 4; ++pass) {
      int rr = ar + pass * 32;
      int row = row0 + rr;
      float4 x = make_float4(0.f, 0.f, 0.f, 0.f);
      if (row < Mrows) x = *(const float4*)(X + (size_t)row * DDIM + k0 + ac);
      unsigned int ux = __float_as_uint(x.x) + 0x8000u;
      unsigned int uy = __float_as_uint(x.y) + 0x8000u;
      unsigned int uz = __float_as_uint(x.z) + 0x8000u;
      unsigned int uw = __float_as_uint(x.w) + 0x8000u;
      *(uint2*)&As[rr][ac] = make_uint2(__builtin_amdgcn_perm(uy, ux, 0x07060302u),
                                        __builtin_amdgcn_perm(uw, uz, 0x07060302u));
    }
#pragma unroll
    for (int pp = 0; pp < 2; ++pp) {
      int rr = br + pp * 64;
      *(uint4*)&Bs[rr][bc] = *(const uint4*)(Wt + (size_t)(n0 + rr) * DDIM + k0 + bc);
    }
    __syncthreads();

    bf16x8 a[4], bfr[4];
#pragma unroll
    for (int mi = 0; mi < 4; ++mi)
      a[mi] = *(const bf16x8*)&As[wm * 64 + mi * 16 + l15][quad * 8];
#pragma unroll
    for (int ni = 0; ni < 4; ++ni)
      bfr[ni] = *(const bf16x8*)&Bs[wn * 64 + ni * 16 + l15][quad * 8];
#pragma unroll
    for (int mi = 0; mi < 4; ++mi)
#pragma unroll
      for (int ni = 0; ni < 4; ++ni)
        acc[mi][ni] = __builtin_amdgcn_mfma_f32_16x16x32_bf16(a[mi], bfr[ni], acc[mi][ni], 0, 0, 0);
    __syncthreads();
  }

  float vvv[4], bbv[4];
#pragma unroll
  for (int ni = 0; ni < 4; ++ni) {
    int n = n0 + wn * 64 + ni * 16 + l15;
    vvv[ni] = vv[n];
    bbv[ni] = bias[n];
  }
#pragma unroll
  for (int mi = 0; mi < 4; ++mi) {
#pragma unroll
    for (int reg = 0; reg < 4; ++reg) {
      float s = 0.f;
#pragma unroll
      for (int ni = 0; ni < 4; ++ni)
        s += tanh_fast(acc[mi][ni][reg] + bbv[ni]) * vvv[ni];
      s += __shfl_xor(s, 1);
      s += __shfl_xor(s, 2);
      s += __shfl_xor(s, 4);
      s += __shfl_xor(s, 8);
      if (l15 == mi * 4 + reg) {
        int row = row0 + wm * 64 + mi * 16 + quad * 4 + reg;
        if (row < Mrows) atomicAdd(&outs[row], s);
      }
    }
  }
}

// ---------------- block reduce helper ----------------
__device__ __forceinline__ float block_reduce(float v, bool is_max, float* redbuf) {
#pragma unroll
  for (int off = 1; off < 64; off <<= 1) {
    float o = __shfl_xor(v, off);
    v = is_max ? fmaxf(v, o) : (v + o);
  }
  int wv = threadIdx.x >> 6;
  if ((threadIdx.x & 63) == 0) redbuf[wv] = v;
  __syncthreads();
  float r = is_max ? fmaxf(fmaxf(redbuf[0], redbuf[1]), fmaxf(redbuf[2], redbuf[3]))
                   : (redbuf[0] + redbuf[1] + redbuf[2] + redbuf[3]);
  __syncthreads();
  return r;
}

// ---------------- kernel: softmax + weighted pooling from compacted bf16 X ----------------
// grid (NPAIR, 8): each chunk-block recomputes the (cheap) two-range softmax,
// then accumulates its l-strided slice of the weighted sums via atomics.
__global__ __launch_bounds__(256) void k_pool2(
    const unsigned short* __restrict__ Xbf, const float* __restrict__ X,
    const float* __restrict__ scores, const int* __restrict__ fsep,
    const int* __restrict__ ssep, const int* __restrict__ off,
    float* __restrict__ emb, float* __restrict__ out) {
  const int p = blockIdx.x, c = blockIdx.y, t = threadIdx.x;
  const int fs = fsep[p], ss = ssep[p];
  __shared__ float sw1[LSEQ], sw2[LSEQ];
  __shared__ float redbuf[4];

  float m1p = -INFINITY, m2p = -INFINITY;
  for (int l = t; l < LSEQ; l += 256) {
    float s = scores[p * LSEQ + l];
    float s1 = (l >= 1 && l < fs) ? s : -INFINITY;
    float s2 = (l > fs && l < ss) ? s : -INFINITY;
    sw1[l] = s1; sw2[l] = s2;
    m1p = fmaxf(m1p, s1); m2p = fmaxf(m2p, s2);
  }
  __syncthreads();
  float m1 = block_reduce(m1p, true, redbuf);
  float m2 = block_reduce(m2p, true, redbuf);
  float d1p = 0.f, d2p = 0.f;
  for (int l = t; l < LSEQ; l += 256) {
    float e1v = __expf(sw1[l] - m1);
    float e2v = __expf(sw2[l] - m2);
    sw1[l] = e1v; sw2[l] = e2v;
    d1p += e1v; d2p += e2v;
  }
  __syncthreads();
  float inv1 = 1.f / block_reduce(d1p, false, redbuf);
  float inv2 = 1.f / block_reduce(d2p, false, redbuf);

  if (c == 0 && t < 192) {  // pair_embeddings = all_output[:, 0, :] (exact fp32 copy)
    *(float4*)(out + (size_t)p * DDIM + t * 4) =
        *(const float4*)(X + (size_t)p * LSEQ * DDIM + t * 4);
  }

  if (t < 192) {
    const int o = off[p];
    float A1[4] = {0.f, 0.f, 0.f, 0.f}, A2[4] = {0.f, 0.f, 0.f, 0.f};
    for (int l = 1 + c; l < ss; l += 8) {
      float wa = sw1[l] * inv1, wb = sw2[l] * inv2;
      uint2 xv = *(const uint2*)(Xbf + (size_t)(o + l - 1) * DDIM + t * 4);
      float x0 = __uint_as_float((xv.x & 0xFFFFu) << 16);
      float x1 = __uint_as_float(xv.x & 0xFFFF0000u);
      float x2 = __uint_as_float((xv.y & 0xFFFFu) << 16);
      float x3 = __uint_as_float(xv.y & 0xFFFF0000u);
      A1[0] += wa * x0; A1[1] += wa * x1; A1[2] += wa * x2; A1[3] += wa * x3;
      A2[0] += wb * x0; A2[1] += wb * x1; A2[2] += wb * x2; A2[3] += wb * x3;
    }
    float* e1 = emb + (size_t)(2 * p) * DDIM + t * 4;
    float* e2 = emb + (size_t)(2 * p + 1) * DDIM + t * 4;
#pragma unroll
    for (int i = 0; i < 4; ++i) atomicAdd(&e1[i], A1[i]);
#pragma unroll
    for (int i = 0; i < 4; ++i) atomicAdd(&e2[i], A2[i]);
  }
}

// ---------------- fallback pooling (R3) ----------------
__global__ __launch_bounds__(256) void k_pool(
    const float* __restrict__ X, const float* __restrict__ scores,
    const int* __restrict__ fsep, const int* __restrict__ ssep,
    float* __restrict__ emb, float* __restrict__ out) {
  const int p = blockIdx.x;
  const int c = blockIdx.y;
  const int t = threadIdx.x;
  const int fs = fsep[p], ss = ssep[p];
  __shared__ float sw1[LSEQ], sw2[LSEQ];
  __shared__ float redbuf[4];

  float m1p = -INFINITY, m2p = -INFINITY;
  for (int l = t; l < LSEQ; l += 256) {
    float s = scores[p * LSEQ + l];
    float s1 = (l >= 1 && l < fs) ? s : -INFINITY;
    float s2 = (l > fs && l < ss) ? s : -INFINITY;
    sw1[l] = s1; sw2[l] = s2;
    m1p = fmaxf(m1p, s1); m2p = fmaxf(m2p, s2);
  }
  __syncthreads();
  float m1 = block_reduce(m1p, true, redbuf);
  float m2 = block_reduce(m2p, true, redbuf);
  float d1p = 0.f, d2p = 0.f;
  for (int l = t; l < LSEQ; l += 256) {
    float e1v = __expf(sw1[l] - m1);
    float e2v = __expf(sw2[l] - m2);
    sw1[l] = e1v; sw2[l] = e2v;
    d1p += e1v; d2p += e2v;
  }
  __syncthreads();
  float inv1 = 1.f / block_reduce(d1p, false, redbuf);
  float inv2 = 1.f / block_reduce(d2p, false, redbuf);
  const float* base = X + (size_t)p * LSEQ * DDIM;
  if (c == 0) {
    float* po = out + (size_t)p * DDIM;
    po[t] = base[t]; po[t + 256] = base[t + 256]; po[t + 512] = base[t + 512];
  }
  if (t < 192) {
    float4 A1 = make_float4(0.f, 0.f, 0.f, 0.f);
    float4 A2 = make_float4(0.f, 0.f, 0.f, 0.f);
    for (int l = 1 + c; l < ss; l += 8) {
      float wa = sw1[l] * inv1, wb = sw2[l] * inv2;
      float4 x = *(const float4*)(base + (size_t)l * DDIM + 4 * t);
      A1.x += wa * x.x; A1.y += wa * x.y; A1.z += wa * x.z; A1.w += wa * x.w;
      A2.x += wb * x.x; A2.y += wb * x.y; A2.z += wb * x.z; A2.w += wb * x.w;
    }
    float* e1 = emb + (size_t)(2 * p) * DDIM + 4 * t;
    float* e2 = emb + (size_t)(2 * p + 1) * DDIM + 4 * t;
    atomicAdd(&e1[0], A1.x); atomicAdd(&e1[1], A1.y);
    atomicAdd(&e1[2], A1.z); atomicAdd(&e1[3], A1.w);
    atomicAdd(&e2[0], A2.x); atomicAdd(&e2[1], A2.y);
    atomicAdd(&e2[2], A2.z); atomicAdd(&e2[3], A2.w);
  }
}

// ---------------- kernel: segment softmax + weighted sum ----------------
__global__ __launch_bounds__(256) void k_segout(
    const float* __restrict__ emb, const float* __restrict__ sc,
    float* __restrict__ out2) {
  const int g = blockIdx.x;  // 0..31
  const int z = g >> 3, j = g & 7;
  const int t = threadIdx.x;
  int ee[14];
#pragma unroll
  for (int i = 0; i < 7; ++i) ee[i] = 2 * (z * 56 + j * 7 + i);
#pragma unroll
  for (int i = 0; i < 7; ++i) {
    int j2 = i + (i >= j ? 1 : 0);
    int kk = j - (j > j2 ? 1 : 0);
    ee[7 + i] = 2 * (z * 56 + j2 * 7 + kk) + 1;
  }
  float sv[14];
  float m = -INFINITY;
#pragma unroll
  for (int i = 0; i < 14; ++i) { sv[i] = sc[ee[i]]; m = fmaxf(m, sv[i]); }
  float den = 0.f;
#pragma unroll
  for (int i = 0; i < 14; ++i) { sv[i] = __expf(sv[i] - m); den += sv[i]; }
  float inv = 1.f / den;
  float a0 = 0.f, a1 = 0.f, a2 = 0.f;
#pragma unroll
  for (int i = 0; i < 14; ++i) {
    float wgt = sv[i] * inv;
    const float* er = emb + (size_t)ee[i] * DDIM;
    a0 += wgt * er[t]; a1 += wgt * er[t + 256]; a2 += wgt * er[t + 512];
  }
  out2[(size_t)g * DDIM + t] = a0;
  out2[(size_t)g * DDIM + t + 256] = a1;
  out2[(size_t)g * DDIM + t + 512] = a2;
}

// ---------------- launcher ----------------
extern "C" void kernel_launch(void* const* d_in, const int* in_sizes, int n_in,
                              void* d_out, int out_size, void* d_ws, size_t ws_size,
                              hipStream_t stream) {
  const float* X  = (const float*)d_in[0];
  const int* fs   = (const int*)d_in[1];
  const int* ss   = (const int*)d_in[2];
  const float* W1 = (const float*)d_in[3];
  const float* b1 = (const float*)d_in[4];
  const float* v1 = (const float*)d_in[5];
  const float* W2 = (const float*)d_in[7];
  const float* b2 = (const float*)d_in[8];
  const float* v2 = (const float*)d_in[9];
  float* out = (float*)d_out;

  char* ws = (char*)d_ws;
  // fast-path layout (all offsets 256-B aligned)
  const size_t XBF_ROWS = (size_t)MAXSLAB * 128 + 64;          // 66,624 pad rows
  const size_t OFF_MAP  = XBF_ROWS * DDIM * 2;                 // 102,334,464
  const size_t OFF_OFF  = OFF_MAP + XBF_ROWS * 4;              // +266,496 -> 102,600,960
  const size_t OFF_WT1  = OFF_OFF + 1024;
  const size_t OFF_WT2  = OFF_WT1 + 1179648;
  const size_t OFF_SCORES = OFF_WT2 + 1179648;
  const size_t OFF_EMB  = OFF_SCORES + 313600;
  const size_t OFF_SC   = OFF_EMB + 1376256;
  const size_t NEED     = OFF_SC + 2048;  // ~106.7 MB

  if (ws_size >= NEED) {
    unsigned short* Xbf = (unsigned short*)ws;
    int*   rowmap = (int*)(ws + OFF_MAP);
    int*   off    = (int*)(ws + OFF_OFF);
    unsigned short* Wt1 = (unsigned short*)(ws + OFF_WT1);
    unsigned short* Wt2 = (unsigned short*)(ws + OFF_WT2);
    float* scores = (float*)(ws + OFF_SCORES);
    float* emb    = (float*)(ws + OFF_EMB);
    float* sc     = (float*)(ws + OFF_SC);

    k_scan<<<1, 256, 0, stream>>>(ss, off);
    k_wt2<<<dim3(24, 24, 2), 256, 0, stream>>>(W1, W2, Wt1, Wt2);
    // scores | emb | sc are contiguous: one memset
    hipMemsetAsync(scores, 0, 313600 + 1376256 + 2048, stream);
    k_conv<<<dim3(NPAIR, 3, 4), 256, 0, stream>>>(X, ss, off, Xbf, rowmap);
    k_gemm_c<<<65 * 48, 256, 0, stream>>>(Xbf, Wt1, b1, v1, off, rowmap, scores);
    k_pool2<<<dim3(NPAIR, 8), 256, 0, stream>>>(Xbf, X, scores, fs, ss, off, emb, out);
    k_gemm_score<<<dim3(6, 4), 256, 0, stream>>>(emb, Wt2, b2, v2, sc, 448, 0);
    k_segout<<<32, 256, 0, stream>>>(emb, sc, out + (size_t)NPAIR * DDIM);
  } else {
    // fallback (R3 path, ~2.9 MB ws)
    unsigned short* Wt = (unsigned short*)ws;
    float* scores = (float*)(ws + 1179648);
    float* emb    = (float*)(ws + 1493248);
    float* sc     = scores;

    k_w1t<<<dim3(24, 24), 256, 0, stream>>>(W1, Wt);
    hipMemsetAsync(scores, 0, MROWS1 * sizeof(float), stream);
    hipMemsetAsync(emb, 0, 448 * DDIM * sizeof(float), stream);
    k_gemm_score<<<77 * 48, 256, 0, stream>>>(X, Wt, b1, v1, scores, MROWS1, 1);
    k_pool<<<dim3(NPAIR, 8), 256, 0, stream>>>(X, scores, fs, ss, emb, out);
    k_w1t<<<dim3(24, 24), 256, 0, stream>>>(W2, Wt);
    hipMemsetAsync(sc, 0, 448 * sizeof(float), stream);
    k_gemm_score<<<dim3(6, 4), 256, 0, stream>>>(emb, Wt, b2, v2, sc, 448, 0);
    k_segout<<<32, 256, 0, stream>>>(emb, sc, out + (size_t)NPAIR * DDIM);
  }
}

// Round 6
// 489.146 us; speedup vs baseline: 1.4285x; 1.0222x over previous
//
#include <hip/hip_runtime.h>
#include <math.h>

#define LSEQ   350
#define DDIM   768
#define NPAIR  224
#define MROWS1 78400
#define NSLAB1 613      // fallback path
#define MAXSLAB 520     // ceil(224*297/128) worst-case compacted slabs

typedef short bf16x8 __attribute__((ext_vector_type(8)));
typedef float f32x4  __attribute__((ext_vector_type(4)));

typedef const unsigned int __attribute__((address_space(1)))* gas_ptr;
typedef unsigned int __attribute__((address_space(3)))* las_ptr;

__device__ __forceinline__ void gload_lds16(const void* g, void* l) {
  __builtin_amdgcn_global_load_lds((gas_ptr)g, (las_ptr)l, 16, 0, 0);
}

__device__ __forceinline__ unsigned short f2bf(float x) {
  unsigned int u = __float_as_uint(x);
  unsigned int r = (u + 0x7FFFu + ((u >> 16) & 1u)) >> 16;  // RNE
  return (unsigned short)r;
}

__device__ __forceinline__ float tanh_fast(float x) {
  float e = __expf(2.f * x);
  return 1.f - 2.f / (e + 1.f);
}

// ---------------- kernel: fused prep ----------------
// blocks [0,1152): W1/W2 -> Wt1/Wt2 transpose+bf16 (576 each)
// block 1152: exclusive prefix scan of (ss[p]-1) -> off[0..NPAIR]
// blocks (1152, 1152+263]: zero scores_c|sc region (263 KiB)
#define PREP_WT 1152
#define PREP_ZB 263
__global__ __launch_bounds__(256) void k_prep(
    const float* __restrict__ W1, const float* __restrict__ W2,
    unsigned short* __restrict__ Wt1, unsigned short* __restrict__ Wt2,
    const int* __restrict__ ssep, int* __restrict__ off,
    unsigned int* __restrict__ zreg) {
  const int b = blockIdx.x;
  const int t = threadIdx.x;
  if (b < PREP_WT) {
    const float* W = (b >= 576) ? W2 : W1;
    unsigned short* Wt = (b >= 576) ? Wt2 : Wt1;
    const int r = (b >= 576) ? b - 576 : b;
    const int bk = (r % 24) * 32, bn = (r / 24) * 32;
    __shared__ float tile[32][33];
    const int tx = t & 31, ty = t >> 5;
#pragma unroll
    for (int i = 0; i < 32; i += 8)
      tile[ty + i][tx] = W[(size_t)(bk + ty + i) * DDIM + bn + tx];
    __syncthreads();
#pragma unroll
    for (int i = 0; i < 32; i += 8)
      Wt[(size_t)(bn + ty + i) * DDIM + bk + tx] = f2bf(tile[tx][ty + i]);
  } else if (b == PREP_WT) {
    __shared__ int buf[256];
    int v = (t < NPAIR) ? (ssep[t] - 1) : 0;
    buf[t] = v;
    __syncthreads();
#pragma unroll
    for (int d = 1; d < 256; d <<= 1) {
      int add = (t >= d) ? buf[t - d] : 0;
      __syncthreads();
      buf[t] += add;
      __syncthreads();
    }
    if (t < NPAIR) off[t] = buf[t] - v;          // exclusive
    if (t == NPAIR - 1) off[NPAIR] = buf[t];     // total compacted rows
  } else {
    const int i = b - PREP_WT - 1;
    zreg[(size_t)i * 256 + t] = 0u;
  }
}

// ---------------- kernel: X -> compacted Xbf (bf16) ----------------
// grid (NPAIR, 3, 4) x 192. Pair p rows l=1..ss[p]-1 land at Xbf[off[p]+l-1].
__global__ __launch_bounds__(192) void k_conv(const float* __restrict__ X,
                                              const int* __restrict__ ssep,
                                              const int* __restrict__ off,
                                              unsigned short* __restrict__ Xbf) {
  const int p = blockIdx.x, tile = blockIdx.y, z = blockIdx.z;
  const int nrow = ssep[p] - 1;
  const int r0 = tile * 128 + z * 32;
  if (r0 >= nrow) return;
  const int t = threadIdx.x;
  const int o = off[p];
  const int rmax = min(32, nrow - r0);
  const float* src = X + ((size_t)p * LSEQ + 1 + r0) * DDIM + t * 4;
  unsigned short* dst = Xbf + (size_t)(o + r0) * DDIM + t * 4;
#pragma unroll 4
  for (int i = 0; i < rmax; ++i) {
    float4 x = *(const float4*)(src + (size_t)i * DDIM);
    unsigned int ux = __float_as_uint(x.x) + 0x8000u;
    unsigned int uy = __float_as_uint(x.y) + 0x8000u;
    unsigned int uz = __float_as_uint(x.z) + 0x8000u;
    unsigned int uw = __float_as_uint(x.w) + 0x8000u;
    *(uint2*)(dst + (size_t)i * DDIM) =
        make_uint2(__builtin_amdgcn_perm(uy, ux, 0x07060302u),
                   __builtin_amdgcn_perm(uw, uz, 0x07060302u));
  }
}

// ---------------- kernel: compacted bf16 GEMM + tanh-dot epilogue ----------------
// grid = 65*48. decode: g=b/48, r=b%48; slab=g*8+(r&7), nchunk=r>>3. The 6 nchunks
// of one slab run consecutively on the SAME XCD (round-robin %8) -> A-slab from L2.
// m97 structure: global_load_lds width 16, unpadded 128x32 LDS tiles.
__global__ __launch_bounds__(256, 4) void k_gemm_c(
    const unsigned short* __restrict__ Xbf, const unsigned short* __restrict__ Wt,
    const float* __restrict__ bias, const float* __restrict__ vv,
    const int* __restrict__ off, float* __restrict__ scores_c) {
  const int Mtotal = off[NPAIR];
  const int b = blockIdx.x;
  const int g = b / 48, r = b - g * 48;
  const int slab = g * 8 + (r & 7);
  const int nchunk = r >> 3;
  if (slab * 128 >= Mtotal) return;  // uniform, before any barrier

  const size_t arow0 = (size_t)slab * 128;
  const int n0 = nchunk * 128;

  __shared__ unsigned short As[128 * 32];
  __shared__ unsigned short Bs[128 * 32];

  const int t = threadIdx.x;
  const int lane = t & 63, w = t >> 6;
  const int l15 = t & 15;
  const int quad = (t >> 4) & 3;
  const int wm = w >> 1, wn = w & 1;
  const int lrow = lane >> 2;       // DMA: row within 16-row segment
  const int lcol = (lane & 3) * 8;  // DMA: k offset (8 bf16 = 16 B)

  f32x4 acc[4][4];
#pragma unroll
  for (int mi = 0; mi < 4; ++mi)
#pragma unroll
    for (int ni = 0; ni < 4; ++ni)
#pragma unroll
      for (int q = 0; q < 4; ++q) acc[mi][ni][q] = 0.f;

  for (int k0 = 0; k0 < DDIM; k0 += 32) {
#pragma unroll
    for (int j = 0; j < 2; ++j) {
      int seg = w * 2 + j;
      gload_lds16(Xbf + (arow0 + seg * 16 + lrow) * DDIM + k0 + lcol, As + seg * 512);
      gload_lds16(Wt + (size_t)(n0 + seg * 16 + lrow) * DDIM + k0 + lcol, Bs + seg * 512);
    }
    __syncthreads();

    bf16x8 a[4], bfr[4];
#pragma unroll
    for (int mi = 0; mi < 4; ++mi)
      a[mi] = *(const bf16x8*)&As[(wm * 64 + mi * 16 + l15) * 32 + quad * 8];
#pragma unroll
    for (int ni = 0; ni < 4; ++ni)
      bfr[ni] = *(const bf16x8*)&Bs[(wn * 64 + ni * 16 + l15) * 32 + quad * 8];
#pragma unroll
    for (int mi = 0; mi < 4; ++mi)
#pragma unroll
      for (int ni = 0; ni < 4; ++ni)
        acc[mi][ni] = __builtin_amdgcn_mfma_f32_16x16x32_bf16(a[mi], bfr[ni], acc[mi][ni], 0, 0, 0);
    __syncthreads();
  }

  float vvv[4], bbv[4];
#pragma unroll
  for (int ni = 0; ni < 4; ++ni) {
    int n = n0 + wn * 64 + ni * 16 + l15;
    vvv[ni] = vv[n];
    bbv[ni] = bias[n];
  }
#pragma unroll
  for (int mi = 0; mi < 4; ++mi) {
#pragma unroll
    for (int reg = 0; reg < 4; ++reg) {
      float s = 0.f;
#pragma unroll
      for (int ni = 0; ni < 4; ++ni)
        s += tanh_fast(acc[mi][ni][reg] + bbv[ni]) * vvv[ni];
      s += __shfl_xor(s, 1);
      s += __shfl_xor(s, 2);
      s += __shfl_xor(s, 4);
      s += __shfl_xor(s, 8);
      if (l15 == mi * 4 + reg) {
        int row = (int)arow0 + wm * 64 + mi * 16 + quad * 4 + reg;
        if (row < Mtotal) atomicAdd(&scores_c[row], s);
      }
    }
  }
}

// ---------------- fallback big GEMM (R3): fused fp32->bf16 staging ----------------
__global__ __launch_bounds__(256, 2) void k_gemm_score(
    const float* __restrict__ X, const unsigned short* __restrict__ Wt,
    const float* __restrict__ bias, const float* __restrict__ vv,
    float* __restrict__ outs, int Mrows, int swz) {
  int slab, nchunk;
  if (swz) {
    int b = blockIdx.x;
    int g = b / 48, r = b - g * 48;
    slab = g * 8 + (r & 7);
    nchunk = r >> 3;
    if (slab >= NSLAB1) return;
  } else {
    slab = blockIdx.y;
    nchunk = blockIdx.x;
  }
  const int row0 = slab * 128;
  const int n0 = nchunk * 128;

  __shared__ unsigned short As[128][40];
  __shared__ unsigned short Bs[128][40];

  const int t = threadIdx.x;
  const int l15 = t & 15;
  const int quad = (t >> 4) & 3;
  const int w = t >> 6;
  const int wm = w >> 1, wn = w & 1;
  const int ar = t >> 3;
  const int ac = (t & 7) * 4;
  const int br = t >> 2;
  const int bc = (t & 3) * 8;

  f32x4 acc[4][4];
#pragma unroll
  for (int mi = 0; mi < 4; ++mi)
#pragma unroll
    for (int ni = 0; ni < 4; ++ni)
#pragma unroll
      for (int q = 0; q < 4; ++q) acc[mi][ni][q] = 0.f;

  for (int k0 = 0; k0 < DDIM; k0 += 32) {
#pragma unroll
    for (int pass = 0; pass < 4; ++pass) {
      int rr = ar + pass * 32;
      int row = row0 + rr;
      float4 x = make_float4(0.f, 0.f, 0.f, 0.f);
      if (row < Mrows) x = *(const float4*)(X + (size_t)row * DDIM + k0 + ac);
      unsigned int ux = __float_as_uint(x.x) + 0x8000u;
      unsigned int uy = __float_as_uint(x.y) + 0x8000u;
      unsigned int uz = __float_as_uint(x.z) + 0x8000u;
      unsigned int uw = __float_as_uint(x.w) + 0x8000u;
      *(uint2*)&As[rr][ac] = make_uint2(__builtin_amdgcn_perm(uy, ux, 0x07060302u),
                                        __builtin_amdgcn_perm(uw, uz, 0x07060302u));
    }
#pragma unroll
    for (int pp = 0; pp < 2; ++pp) {
      int rr = br + pp * 64;
      *(uint4*)&Bs[rr][bc] = *(const uint4*)(Wt + (size_t)(n0 + rr) * DDIM + k0 + bc);
    }
    __syncthreads();

    bf16x8 a[4], bfr[4];
#pragma unroll
    for (int mi = 0; mi < 4; ++mi)
      a[mi] = *(const bf16x8*)&As[wm * 64 + mi * 16 + l15][quad * 8];
#pragma unroll
    for (int ni = 0; ni < 4; ++ni)
      bfr[ni] = *(const bf16x8*)&Bs[wn * 64 + ni * 16 + l15][quad * 8];
#pragma unroll
    for (int mi = 0; mi < 4; ++mi)
#pragma unroll
      for (int ni = 0; ni < 4; ++ni)
        acc[mi][ni] = __builtin_amdgcn_mfma_f32_16x16x32_bf16(a[mi], bfr[ni], acc[mi][ni], 0, 0, 0);
    __syncthreads();
  }

  float vvv[4], bbv[4];
#pragma unroll
  for (int ni = 0; ni < 4; ++ni) {
    int n = n0 + wn * 64 + ni * 16 + l15;
    vvv[ni] = vv[n];
    bbv[ni] = bias[n];
  }
#pragma unroll
  for (int mi = 0; mi < 4; ++mi) {
#pragma unroll
    for (int reg = 0; reg < 4; ++reg) {
      float s = 0.f;
#pragma unroll
      for (int ni = 0; ni < 4; ++ni)
        s += tanh_fast(acc[mi][ni][reg] + bbv[ni]) * vvv[ni];
      s += __shfl_xor(s, 1);
      s += __shfl_xor(s, 2);
      s += __shfl_xor(s, 4);
      s += __shfl_xor(s, 8);
      if (l15 == mi * 4 + reg) {
        int row = row0 + wm * 64 + mi * 16 + quad * 4 + reg;
        if (row < Mrows) atomicAdd(&outs[row], s);
      }
    }
  }
}

// ---------------- block reduce helper (256 threads / 4 waves) ----------------
__device__ __forceinline__ float block_reduce(float v, bool is_max, float* redbuf) {
#pragma unroll
  for (int off = 1; off < 64; off <<= 1) {
    float o = __shfl_xor(v, off);
    v = is_max ? fmaxf(v, o) : (v + o);
  }
  int wv = threadIdx.x >> 6;
  if ((threadIdx.x & 63) == 0) redbuf[wv] = v;
  __syncthreads();
  float r = is_max ? fmaxf(fmaxf(redbuf[0], redbuf[1]), fmaxf(redbuf[2], redbuf[3]))
                   : (redbuf[0] + redbuf[1] + redbuf[2] + redbuf[3]);
  __syncthreads();
  return r;
}

// ---------------- kernel: softmax + pooling, one block per pair, no atomics ----------------
__global__ __launch_bounds__(256) void k_pool3(
    const unsigned short* __restrict__ Xbf, const float* __restrict__ X,
    const float* __restrict__ scores_c, const int* __restrict__ fsep,
    const int* __restrict__ ssep, const int* __restrict__ off,
    float* __restrict__ emb, float* __restrict__ out) {
  const int p = blockIdx.x, t = threadIdx.x;
  const int fs = fsep[p], ss = ssep[p];
  const int o = off[p];
  __shared__ float sw1[LSEQ], sw2[LSEQ];
  __shared__ float redbuf[4];

  float m1p = -INFINITY, m2p = -INFINITY;
  for (int l = t; l < LSEQ; l += 256) {
    float s = (l >= 1 && l < ss) ? scores_c[o + l - 1] : 0.f;
    float s1 = (l >= 1 && l < fs) ? s : -INFINITY;
    float s2 = (l > fs && l < ss) ? s : -INFINITY;
    sw1[l] = s1; sw2[l] = s2;
    m1p = fmaxf(m1p, s1); m2p = fmaxf(m2p, s2);
  }
  __syncthreads();
  float m1 = block_reduce(m1p, true, redbuf);
  float m2 = block_reduce(m2p, true, redbuf);
  float d1p = 0.f, d2p = 0.f;
  for (int l = t; l < LSEQ; l += 256) {
    float e1v = __expf(sw1[l] - m1);
    float e2v = __expf(sw2[l] - m2);
    sw1[l] = e1v; sw2[l] = e2v;
    d1p += e1v; d2p += e2v;
  }
  __syncthreads();
  float inv1 = 1.f / block_reduce(d1p, false, redbuf);
  float inv2 = 1.f / block_reduce(d2p, false, redbuf);

  // all barriers done -- divergent tail is safe
  if (t < 192) {
    // pair_embeddings = all_output[:, 0, :] (exact fp32 copy)
    *(float4*)(out + (size_t)p * DDIM + t * 4) =
        *(const float4*)(X + (size_t)p * LSEQ * DDIM + t * 4);

    float A1[4] = {0.f, 0.f, 0.f, 0.f}, A2[4] = {0.f, 0.f, 0.f, 0.f};
    const unsigned short* xb = Xbf + (size_t)o * DDIM + t * 4;
#pragma unroll 2
    for (int l = 1; l < ss; ++l) {
      float wa = sw1[l] * inv1, wb = sw2[l] * inv2;
      uint2 xv = *(const uint2*)(xb + (size_t)(l - 1) * DDIM);
      float x0 = __uint_as_float((xv.x & 0xFFFFu) << 16);
      float x1 = __uint_as_float(xv.x & 0xFFFF0000u);
      float x2 = __uint_as_float((xv.y & 0xFFFFu) << 16);
      float x3 = __uint_as_float(xv.y & 0xFFFF0000u);
      A1[0] += wa * x0; A1[1] += wa * x1; A1[2] += wa * x2; A1[3] += wa * x3;
      A2[0] += wb * x0; A2[1] += wb * x1; A2[2] += wb * x2; A2[3] += wb * x3;
    }
    *(float4*)(emb + (size_t)(2 * p) * DDIM + t * 4) =
        make_float4(A1[0], A1[1], A1[2], A1[3]);
    *(float4*)(emb + (size_t)(2 * p + 1) * DDIM + t * 4) =
        make_float4(A2[0], A2[1], A2[2], A2[3]);
  }
}

// ---------------- fallback kernels (R3 path) ----------------
__global__ __launch_bounds__(256) void k_w1t(const float* __restrict__ W,
                                             unsigned short* __restrict__ Wt) {
  __shared__ float tile[32][33];
  int bk = blockIdx.x * 32, bn = blockIdx.y * 32;
  int tx = threadIdx.x & 31, ty = threadIdx.x >> 5;
#pragma unroll
  for (int i = 0; i < 32; i += 8)
    tile[ty + i][tx] = W[(size_t)(bk + ty + i) * DDIM + bn + tx];
  __syncthreads();
#pragma unroll
  for (int i = 0; i < 32; i += 8)
    Wt[(size_t)(bn + ty + i) * DDIM + bk + tx] = f2bf(tile[tx][ty + i]);
}

__global__ __launch_bounds__(256) void k_pool(
    const float* __restrict__ X, const float* __restrict__ scores,
    const int* __restrict__ fsep, const int* __restrict__ ssep,
    float* __restrict__ emb, float* __restrict__ out) {
  const int p = blockIdx.x;
  const int c = blockIdx.y;
  const int t = threadIdx.x;
  const int fs = fsep[p], ss = ssep[p];
  __shared__ float sw1[LSEQ], sw2[LSEQ];
  __shared__ float redbuf[4];

  float m1p = -INFINITY, m2p = -INFINITY;
  for (int l = t; l < LSEQ; l += 256) {
    float s = scores[p * LSEQ + l];
    float s1 = (l >= 1 && l < fs) ? s : -INFINITY;
    float s2 = (l > fs && l < ss) ? s : -INFINITY;
    sw1[l] = s1; sw2[l] = s2;
    m1p = fmaxf(m1p, s1); m2p = fmaxf(m2p, s2);
  }
  __syncthreads();
  float m1 = block_reduce(m1p, true, redbuf);
  float m2 = block_reduce(m2p, true, redbuf);
  float d1p = 0.f, d2p = 0.f;
  for (int l = t; l < LSEQ; l += 256) {
    float e1v = __expf(sw1[l] - m1);
    float e2v = __expf(sw2[l] - m2);
    sw1[l] = e1v; sw2[l] = e2v;
    d1p += e1v; d2p += e2v;
  }
  __syncthreads();
  float inv1 = 1.f / block_reduce(d1p, false, redbuf);
  float inv2 = 1.f / block_reduce(d2p, false, redbuf);
  const float* base = X + (size_t)p * LSEQ * DDIM;
  if (c == 0) {
    float* po = out + (size_t)p * DDIM;
    po[t] = base[t]; po[t + 256] = base[t + 256]; po[t + 512] = base[t + 512];
  }
  if (t < 192) {
    float4 A1 = make_float4(0.f, 0.f, 0.f, 0.f);
    float4 A2 = make_float4(0.f, 0.f, 0.f, 0.f);
    for (int l = 1 + c; l < ss; l += 8) {
      float wa = sw1[l] * inv1, wb = sw2[l] * inv2;
      float4 x = *(const float4*)(base + (size_t)l * DDIM + 4 * t);
      A1.x += wa * x.x; A1.y += wa * x.y; A1.z += wa * x.z; A1.w += wa * x.w;
      A2.x += wb * x.x; A2.y += wb * x.y; A2.z += wb * x.z; A2.w += wb * x.w;
    }
    float* e1 = emb + (size_t)(2 * p) * DDIM + 4 * t;
    float* e2 = emb + (size_t)(2 * p + 1) * DDIM + 4 * t;
    atomicAdd(&e1[0], A1.x); atomicAdd(&e1[1], A1.y);
    atomicAdd(&e1[2], A1.z); atomicAdd(&e1[3], A1.w);
    atomicAdd(&e2[0], A2.x); atomicAdd(&e2[1], A2.y);
    atomicAdd(&e2[2], A2.z); atomicAdd(&e2[3], A2.w);
  }
}

// ---------------- kernel: segment softmax + weighted sum ----------------
__global__ __launch_bounds__(256) void k_segout(
    const float* __restrict__ emb, const float* __restrict__ sc,
    float* __restrict__ out2) {
  const int g = blockIdx.x;  // 0..31
  const int z = g >> 3, j = g & 7;
  const int t = threadIdx.x;
  int ee[14];
#pragma unroll
  for (int i = 0; i < 7; ++i) ee[i] = 2 * (z * 56 + j * 7 + i);
#pragma unroll
  for (int i = 0; i < 7; ++i) {
    int j2 = i + (i >= j ? 1 : 0);
    int kk = j - (j > j2 ? 1 : 0);
    ee[7 + i] = 2 * (z * 56 + j2 * 7 + kk) + 1;
  }
  float sv[14];
  float m = -INFINITY;
#pragma unroll
  for (int i = 0; i < 14; ++i) { sv[i] = sc[ee[i]]; m = fmaxf(m, sv[i]); }
  float den = 0.f;
#pragma unroll
  for (int i = 0; i < 14; ++i) { sv[i] = __expf(sv[i] - m); den += sv[i]; }
  float inv = 1.f / den;
  float a0 = 0.f, a1 = 0.f, a2 = 0.f;
#pragma unroll
  for (int i = 0; i < 14; ++i) {
    float wgt = sv[i] * inv;
    const float* er = emb + (size_t)ee[i] * DDIM;
    a0 += wgt * er[t]; a1 += wgt * er[t + 256]; a2 += wgt * er[t + 512];
  }
  out2[(size_t)g * DDIM + t] = a0;
  out2[(size_t)g * DDIM + t + 256] = a1;
  out2[(size_t)g * DDIM + t + 512] = a2;
}

// ---------------- launcher ----------------
extern "C" void kernel_launch(void* const* d_in, const int* in_sizes, int n_in,
                              void* d_out, int out_size, void* d_ws, size_t ws_size,
                              hipStream_t stream) {
  const float* X  = (const float*)d_in[0];
  const int* fs   = (const int*)d_in[1];
  const int* ss   = (const int*)d_in[2];
  const float* W1 = (const float*)d_in[3];
  const float* b1 = (const float*)d_in[4];
  const float* v1 = (const float*)d_in[5];
  const float* W2 = (const float*)d_in[7];
  const float* b2 = (const float*)d_in[8];
  const float* v2 = (const float*)d_in[9];
  float* out = (float*)d_out;

  char* ws = (char*)d_ws;
  // fast-path layout (256-B aligned)
  const size_t XBF_ROWS = (size_t)MAXSLAB * 128 + 128;           // 66,688 rows (128 pad)
  const size_t OFF_OFF  = XBF_ROWS * DDIM * 2;                   // 102,432,768
  const size_t OFF_WT1  = OFF_OFF + 1024;
  const size_t OFF_WT2  = OFF_WT1 + 1179648;
  const size_t OFF_SCC  = OFF_WT2 + 1179648;                     // scores_c: 66,688*4 = 266,752
  const size_t OFF_SC2  = OFF_SCC + 266752;                      // sc: 448*4 -> pad
  const size_t ZBYTES   = (size_t)PREP_ZB * 1024;                // 269,312 zeroed (covers scc+sc)
  const size_t OFF_EMB  = OFF_SCC + ZBYTES;
  const size_t NEED     = OFF_EMB + 1376256;                     // ~106.3 MB

  if (ws_size >= NEED) {
    unsigned short* Xbf = (unsigned short*)ws;
    int*   off     = (int*)(ws + OFF_OFF);
    unsigned short* Wt1 = (unsigned short*)(ws + OFF_WT1);
    unsigned short* Wt2 = (unsigned short*)(ws + OFF_WT2);
    float* scores_c = (float*)(ws + OFF_SCC);
    float* sc       = (float*)(ws + OFF_SC2);
    float* emb      = (float*)(ws + OFF_EMB);

    k_prep<<<PREP_WT + 1 + PREP_ZB, 256, 0, stream>>>(
        W1, W2, Wt1, Wt2, ss, off, (unsigned int*)scores_c);
    k_conv<<<dim3(NPAIR, 3, 4), 192, 0, stream>>>(X, ss, off, Xbf);
    k_gemm_c<<<65 * 48, 256, 0, stream>>>(Xbf, Wt1, b1, v1, off, scores_c);
    k_pool3<<<NPAIR, 256, 0, stream>>>(Xbf, X, scores_c, fs, ss, off, emb, out);
    k_gemm_score<<<dim3(6, 4), 256, 0, stream>>>(emb, Wt2, b2, v2, sc, 448, 0);
    k_segout<<<32, 256, 0, stream>>>(emb, sc, out + (size_t)NPAIR * DDIM);
  } else {
    // fallback (R3 path, ~2.9 MB ws)
    unsigned short* Wt = (unsigned short*)ws;
    float* scores = (float*)(ws + 1179648);
    float* emb    = (float*)(ws + 1493248);
    float* sc     = scores;

    k_w1t<<<dim3(24, 24), 256, 0, stream>>>(W1, Wt);
    hipMemsetAsync(scores, 0, MROWS1 * sizeof(float), stream);
    hipMemsetAsync(emb, 0, 448 * DDIM * sizeof(float), stream);
    k_gemm_score<<<77 * 48, 256, 0, stream>>>(X, Wt, b1, v1, scores, MROWS1, 1);
    k_pool<<<dim3(NPAIR, 8), 256, 0, stream>>>(X, scores, fs, ss, emb, out);
    k_w1t<<<dim3(24, 24), 256, 0, stream>>>(W2, Wt);
    hipMemsetAsync(sc, 0, 448 * sizeof(float), stream);
    k_gemm_score<<<dim3(6, 4), 256, 0, stream>>>(emb, Wt, b2, v2, sc, 448, 0);
    k_segout<<<32, 256, 0, stream>>>(emb, sc, out + (size_t)NPAIR * DDIM);
  }
}